// Round 1
// baseline (1070.795 us; speedup 1.0000x reference)
//
#include <hip/hip_runtime.h>
#include <math.h>

// Problem constants (match reference)
#define B_    4
#define T_    2048
#define D_    1024
#define F_    4096
#define R_    (B_*T_)      // 8192 rows (b,t)
#define SEG_  16           // segments per time-chain
#define L_    (T_/SEG_)    // 128 steps per segment
#define DECAYF 0.9f
#define OMDF   0.1f        // 1 - decay
// Flag threshold deliberately below 0.5 so the fallback (which re-tests at
// exactly 0.5) can never miss a spike the flags skipped. fp32 GEMM order
// differences are ~1e-5; margin 0.05 is enormous.
#define FLAG_THRESH 0.45f

// ---------------------------------------------------------------------------
// K0: zero per-row spike flags (ws is poisoned 0xAA before every call)
__global__ void k0_zero_flags(unsigned int* __restrict__ flags) {
    int i = blockIdx.x * blockDim.x + threadIdx.x;
    if (i < R_) flags[i] = 0u;
}

// ---------------------------------------------------------------------------
// K1a: per-segment local EMA of spikes (zero initial state per segment).
// tid layout: tid = (b*SEG_ + s)*D_ + d  -> consecutive tid = consecutive d
// so every global access is fully coalesced.
__global__ void k1a_ema_local(const float* __restrict__ spikes,
                              float* __restrict__ s_ema,
                              float* __restrict__ seg_sum) {
    int tid = blockIdx.x * blockDim.x + threadIdx.x;   // B_*SEG_*D_ threads
    int d = tid & (D_ - 1);
    int s = (tid / D_) & (SEG_ - 1);
    int b = tid / (D_ * SEG_);
    const int base = (b * T_ + s * L_) * D_ + d;
    float e = 0.f;
#pragma unroll 4
    for (int k = 0; k < L_; ++k) {
        float x = spikes[base + k * D_];
        e = DECAYF * e + OMDF * x;
        s_ema[base + k * D_] = e;
    }
    seg_sum[tid] = e;
}

// K1b: sequential scan across the 16 segments of each (b,d) chain.
// start_state[b][s][d] = EMA state entering segment s.
__global__ void k1b_seg_scan(const float* __restrict__ seg_sum,
                             float* __restrict__ start_state,
                             float dpowL) {
    int tid = blockIdx.x * blockDim.x + threadIdx.x;   // B_*D_ threads
    int d = tid & (D_ - 1);
    int b = tid / D_;
    float carry = 0.f;
    for (int s = 0; s < SEG_; ++s) {
        int idx = (b * SEG_ + s) * D_ + d;
        start_state[idx] = carry;
        carry = dpowL * carry + seg_sum[idx];
    }
}

// K1c: add the segment-entry correction: e[t] = local[t] + d^(k+1) * start
__global__ void k1c_fixup(float* __restrict__ s_ema,
                          const float* __restrict__ start_state) {
    int tid = blockIdx.x * blockDim.x + threadIdx.x;   // B_*SEG_*D_ threads
    int d = tid & (D_ - 1);
    int s = (tid / D_) & (SEG_ - 1);
    int b = tid / (D_ * SEG_);
    const int base = (b * T_ + s * L_) * D_ + d;
    float st = start_state[tid];
    float factor = DECAYF;
#pragma unroll 4
    for (int k = 0; k < L_; ++k) {
        s_ema[base + k * D_] += factor * st;
        factor *= DECAYF;
    }
}

// ---------------------------------------------------------------------------
// K2: mixed = s_ema @ W1^T, epilogue-only (no store of mixed): set per-row
// flag if any element exceeds FLAG_THRESH. fp32 tiled GEMM, 64x64 tile,
// BK=16, 4x4 per-thread microtile, 256 threads.
#define BM 64
#define BN 64
#define BK 16

__global__ __launch_bounds__(256)
void k2_gemm_spikeflags(const float* __restrict__ A,   // s_ema [R_ x D_]
                        const float* __restrict__ Bw,  // W1    [F_ x D_]
                        unsigned int* __restrict__ flags) {
    __shared__ float As[BK][BM + 4];   // stride 68 floats: 16B-aligned rows
    __shared__ float Bs[BK][BN + 4];
    const int m0 = blockIdx.y * BM;
    const int n0 = blockIdx.x * BN;
    const int tid = threadIdx.x;
    const int tx = tid & 15;          // 0..15 -> n micro
    const int ty = tid >> 4;          // 0..15 -> m micro
    const int lrow = tid >> 2;        // 0..63
    const int lcol = (tid & 3) * 4;   // 0,4,8,12

    float acc[4][4] = {};

    for (int k0 = 0; k0 < D_; k0 += BK) {
        float4 av = *(const float4*)&A [(size_t)(m0 + lrow) * D_ + k0 + lcol];
        float4 bv = *(const float4*)&Bw[(size_t)(n0 + lrow) * D_ + k0 + lcol];
        __syncthreads();
        As[lcol + 0][lrow] = av.x;
        As[lcol + 1][lrow] = av.y;
        As[lcol + 2][lrow] = av.z;
        As[lcol + 3][lrow] = av.w;
        Bs[lcol + 0][lrow] = bv.x;
        Bs[lcol + 1][lrow] = bv.y;
        Bs[lcol + 2][lrow] = bv.z;
        Bs[lcol + 3][lrow] = bv.w;
        __syncthreads();
#pragma unroll
        for (int k = 0; k < BK; ++k) {
            float4 a = *(const float4*)&As[k][ty * 4];
            float4 b = *(const float4*)&Bs[k][tx * 4];
            acc[0][0] += a.x * b.x; acc[0][1] += a.x * b.y;
            acc[0][2] += a.x * b.z; acc[0][3] += a.x * b.w;
            acc[1][0] += a.y * b.x; acc[1][1] += a.y * b.y;
            acc[1][2] += a.y * b.z; acc[1][3] += a.y * b.w;
            acc[2][0] += a.z * b.x; acc[2][1] += a.z * b.y;
            acc[2][2] += a.z * b.z; acc[2][3] += a.z * b.w;
            acc[3][0] += a.w * b.x; acc[3][1] += a.w * b.y;
            acc[3][2] += a.w * b.z; acc[3][3] += a.w * b.w;
        }
    }
#pragma unroll
    for (int i = 0; i < 4; ++i) {
        bool any = false;
#pragma unroll
        for (int j = 0; j < 4; ++j) any = any || (acc[i][j] > FLAG_THRESH);
        if (any) atomicOr(&flags[m0 + ty * 4 + i], 1u);
    }
}

// ---------------------------------------------------------------------------
// K4: one block per (b,t) row. Unflagged rows (the overwhelmingly common
// case) write zeros. Flagged rows take the exact slow path: recompute
// mixed for each f, test at exactly 0.5, compute r = sigmoid(spikes.Wr_f),
// accumulate out_row += r * W2[:,f]. Each row owned by one block: no atomics.
__global__ __launch_bounds__(256)
void k4_output(const float* __restrict__ s_ema,
               const float* __restrict__ spikes,
               const float* __restrict__ W1,
               const float* __restrict__ Wr,
               const float* __restrict__ W2,
               const unsigned int* __restrict__ flags,
               float* __restrict__ out) {
    const int row = blockIdx.x;          // 0..R_-1
    const int tid = threadIdx.x;
    float4 o = {0.f, 0.f, 0.f, 0.f};

    if (flags[row] == 0u) {              // wave-uniform branch (per block)
        *(float4*)&out[(size_t)row * D_ + tid * 4] = o;
        return;
    }

    __shared__ float se[D_];
    __shared__ float sp[D_];
    __shared__ float red[256];
    __shared__ int nspk;
    __shared__ int spk_list[256];

    for (int i = tid; i < D_; i += 256) {
        se[i] = s_ema[(size_t)row * D_ + i];
        sp[i] = spikes[(size_t)row * D_ + i];
    }
    if (tid == 0) nspk = 0;
    __syncthreads();

    for (int f0 = 0; f0 < F_; f0 += 256) {
        int f = f0 + tid;
        float mix = 0.f;
        for (int k = 0; k < D_; ++k) mix += se[k] * W1[(size_t)f * D_ + k];
        if (mix > 0.5f) {
            int idx = atomicAdd(&nspk, 1);
            spk_list[idx] = f;
        }
        __syncthreads();
        int n = nspk;
        for (int i = 0; i < n; ++i) {
            int fs = spk_list[i];
            float part = 0.f;
#pragma unroll
            for (int k = 0; k < 4; ++k)
                part += sp[tid * 4 + k] * Wr[(size_t)fs * D_ + tid * 4 + k];
            red[tid] = part;
            __syncthreads();
            for (int sft = 128; sft > 0; sft >>= 1) {
                if (tid < sft) red[tid] += red[tid + sft];
                __syncthreads();
            }
            float r = 1.f / (1.f + expf(-red[0]));
            __syncthreads();
            o.x += r * W2[(size_t)(tid * 4 + 0) * F_ + fs];
            o.y += r * W2[(size_t)(tid * 4 + 1) * F_ + fs];
            o.z += r * W2[(size_t)(tid * 4 + 2) * F_ + fs];
            o.w += r * W2[(size_t)(tid * 4 + 3) * F_ + fs];
        }
        __syncthreads();
        if (tid == 0) nspk = 0;
        __syncthreads();
    }
    *(float4*)&out[(size_t)row * D_ + tid * 4] = o;
}

// ---------------------------------------------------------------------------
extern "C" void kernel_launch(void* const* d_in, const int* in_sizes, int n_in,
                              void* d_out, int out_size, void* d_ws, size_t ws_size,
                              hipStream_t stream) {
    const float* spikes = (const float*)d_in[0];   // [B,T,D]
    const float* W1     = (const float*)d_in[1];   // [F,D]
    const float* W2     = (const float*)d_in[2];   // [D,F]
    const float* Wr     = (const float*)d_in[3];   // [F,D]
    float* out = (float*)d_out;                    // [B,T,D]

    // workspace layout (~34.1 MB total)
    char* ws = (char*)d_ws;
    float* s_ema       = (float*)ws;                               // R_*D_
    float* seg_sum     = (float*)(ws + (size_t)R_ * D_ * 4);       // B_*SEG_*D_
    float* start_state = seg_sum + (size_t)B_ * SEG_ * D_;         // B_*SEG_*D_
    unsigned int* flags = (unsigned int*)(start_state + (size_t)B_ * SEG_ * D_); // R_

    const float dpowL = (float)pow(0.9, (double)L_);   // 0.9^128

    k0_zero_flags<<<(R_ + 255) / 256, 256, 0, stream>>>(flags);
    k1a_ema_local<<<(B_ * SEG_ * D_) / 256, 256, 0, stream>>>(spikes, s_ema, seg_sum);
    k1b_seg_scan<<<(B_ * D_) / 256, 256, 0, stream>>>(seg_sum, start_state, dpowL);
    k1c_fixup<<<(B_ * SEG_ * D_) / 256, 256, 0, stream>>>(s_ema, start_state);

    dim3 g2(F_ / BN, R_ / BM);
    k2_gemm_spikeflags<<<g2, 256, 0, stream>>>(s_ema, W1, flags);

    k4_output<<<R_, 256, 0, stream>>>(s_ema, spikes, W1, Wr, W2, flags, out);
}

// Round 2
// 241.005 us; speedup vs baseline: 4.4430x; 4.4430x over previous
//
#include <hip/hip_runtime.h>
#include <math.h>

// Problem constants (match reference)
#define B_    4
#define T_    2048
#define D_    1024
#define F_    4096
#define R_    (B_*T_)      // 8192 rows (b,t)
#define SEG_  16           // segments per time-chain
#define L_    (T_/SEG_)    // 128 steps per segment
#define DECAYF 0.9f
#define OMDF   0.1f        // 1 - decay
// Flag threshold deliberately below 0.5 so the fallback (which re-tests at
// exactly 0.5 in fp32) can never miss a spike the flags skipped. bf16-input
// GEMM error is bounded ~6e-3 worst case; margin 0.05 is ~10x that.
#define FLAG_THRESH 0.45f

typedef unsigned short ushort_t;
typedef __attribute__((ext_vector_type(8))) __bf16 bf16x8;
typedef __attribute__((ext_vector_type(4))) float f32x4;

__device__ __forceinline__ ushort_t bf16r(float f) {
    unsigned u = __float_as_uint(f);
    unsigned r = (u + 0x7FFFu + ((u >> 16) & 1u)) >> 16;
    return (ushort_t)r;
}

__device__ __forceinline__ void gload_lds16(const void* g, void* l) {
    __builtin_amdgcn_global_load_lds(
        (const __attribute__((address_space(1))) unsigned int*)g,
        (__attribute__((address_space(3))) unsigned int*)l, 16, 0, 0);
}

// ---------------------------------------------------------------------------
// K0: zero per-row spike flags (ws is poisoned 0xAA before every call)
__global__ void k0_zero_flags(unsigned int* __restrict__ flags) {
    int i = blockIdx.x * blockDim.x + threadIdx.x;
    if (i < R_) flags[i] = 0u;
}

// ---------------------------------------------------------------------------
// K1a: per-segment local EMA of spikes (zero initial state per segment).
__global__ void k1a_ema_local(const float* __restrict__ spikes,
                              float* __restrict__ s_ema,
                              float* __restrict__ seg_sum) {
    int tid = blockIdx.x * blockDim.x + threadIdx.x;   // B_*SEG_*D_ threads
    int d = tid & (D_ - 1);
    int s = (tid / D_) & (SEG_ - 1);
    int b = tid / (D_ * SEG_);
    const int base = (b * T_ + s * L_) * D_ + d;
    float e = 0.f;
#pragma unroll 4
    for (int k = 0; k < L_; ++k) {
        float x = spikes[base + k * D_];
        e = DECAYF * e + OMDF * x;
        s_ema[base + k * D_] = e;
    }
    seg_sum[tid] = e;
}

// K1b: sequential scan across the 16 segments of each (b,d) chain.
__global__ void k1b_seg_scan(const float* __restrict__ seg_sum,
                             float* __restrict__ start_state,
                             float dpowL) {
    int tid = blockIdx.x * blockDim.x + threadIdx.x;   // B_*D_ threads
    int d = tid & (D_ - 1);
    int b = tid / D_;
    float carry = 0.f;
    for (int s = 0; s < SEG_; ++s) {
        int idx = (b * SEG_ + s) * D_ + d;
        start_state[idx] = carry;
        carry = dpowL * carry + seg_sum[idx];
    }
}

// K1c: add segment-entry correction e[t] += d^(k+1)*start; emit bf16 copy.
__global__ void k1c_fixup(float* __restrict__ s_ema,
                          const float* __restrict__ start_state,
                          ushort_t* __restrict__ a_bf) {
    int tid = blockIdx.x * blockDim.x + threadIdx.x;   // B_*SEG_*D_ threads
    int d = tid & (D_ - 1);
    int s = (tid / D_) & (SEG_ - 1);
    int b = tid / (D_ * SEG_);
    const int base = (b * T_ + s * L_) * D_ + d;
    float st = start_state[tid];
    float factor = DECAYF;
#pragma unroll 4
    for (int k = 0; k < L_; ++k) {
        float v = s_ema[base + k * D_] + factor * st;
        s_ema[base + k * D_] = v;
        a_bf[base + k * D_] = bf16r(v);
        factor *= DECAYF;
    }
}

// K1w: convert W1 [F_ x D_] fp32 -> bf16 (row-major, k-major rows)
__global__ void k1w_w1_to_bf16(const float* __restrict__ W1,
                               ushort_t* __restrict__ w_bf) {
    int i = blockIdx.x * blockDim.x + threadIdx.x;   // per 4 elements
    float4 v = ((const float4*)W1)[i];
    ushort4 o;
    o.x = bf16r(v.x); o.y = bf16r(v.y); o.z = bf16r(v.z); o.w = bf16r(v.w);
    ((ushort4*)w_bf)[i] = o;
}

// ---------------------------------------------------------------------------
// K2: bf16 MFMA GEMM, flags-only epilogue (C is never materialized).
// 128x128 tile, BK=64, 4 waves in 2x2, each wave 4x4 grid of 16x16x32 MFMAs.
// LDS: k-major rows (128 B/row), 16B chunks XOR-swizzled by (row&7) so both
// the global_load_lds staging (wave-uniform base + lane*16) and the
// ds_read_b128 fragment reads are conflict-free (<=2-way).
__global__ __launch_bounds__(256)
void k2_mfma_flags(const ushort_t* __restrict__ A,    // s_ema bf16 [R_ x D_]
                   const ushort_t* __restrict__ Bw,   // W1 bf16    [F_ x D_]
                   unsigned int* __restrict__ flags) {
    __shared__ ushort_t lA[128 * 64];
    __shared__ ushort_t lB[128 * 64];
    const int tid = threadIdx.x;
    const int w = tid >> 6;
    const int lane = tid & 63;
    const int m0 = blockIdx.y * 128;
    const int n0 = blockIdx.x * 128;
    const int wm = w >> 1, wn = w & 1;

    f32x4 acc[4][4] = {};

    const int rown = lane & 15;
    const int quad = lane >> 4;

    for (int k0 = 0; k0 < D_; k0 += 64) {
        __syncthreads();   // previous iter's LDS reads must complete
        // Stage A and B tiles: 1024 16B-chunks each; 4 rounds x 4 waves x 64 lanes.
#pragma unroll
        for (int r = 0; r < 4; ++r) {
            const int Ibase = r * 256 + w * 64;
            const int I = Ibase + lane;
            const int row = I >> 3;
            const int cl = (I & 7) ^ (row & 7);    // logical chunk for this slot
            gload_lds16(&A [(size_t)(m0 + row) * D_ + k0 + cl * 8], &lA[Ibase * 8]);
            gload_lds16(&Bw[(size_t)(n0 + row) * D_ + k0 + cl * 8], &lB[Ibase * 8]);
        }
        __syncthreads();   // drains vmcnt: staged data visible

#pragma unroll
        for (int kk = 0; kk < 2; ++kk) {
            bf16x8 af[4], bfr[4];
#pragma unroll
            for (int i = 0; i < 4; ++i) {
                const int ra = wm * 64 + i * 16 + rown;
                const int ca = (kk * 4 + quad) ^ (ra & 7);
                af[i] = *(const bf16x8*)&lA[ra * 64 + ca * 8];
                const int rb = wn * 64 + i * 16 + rown;
                const int cb = (kk * 4 + quad) ^ (rb & 7);
                bfr[i] = *(const bf16x8*)&lB[rb * 64 + cb * 8];
            }
#pragma unroll
            for (int i = 0; i < 4; ++i)
#pragma unroll
                for (int j = 0; j < 4; ++j)
                    acc[i][j] = __builtin_amdgcn_mfma_f32_16x16x32_bf16(
                        af[i], bfr[j], acc[i][j], 0, 0, 0);
        }
    }

    // Epilogue: per-row spike flags. C/D layout: col=lane&15, row=quad*4+reg.
#pragma unroll
    for (int i = 0; i < 4; ++i) {
#pragma unroll
        for (int v = 0; v < 4; ++v) {
            float mx =        acc[i][0][v];
            mx = fmaxf(mx,    acc[i][1][v]);
            mx = fmaxf(mx,    acc[i][2][v]);
            mx = fmaxf(mx,    acc[i][3][v]);
            if (mx > FLAG_THRESH)
                atomicOr(&flags[m0 + wm * 64 + i * 16 + quad * 4 + v], 1u);
        }
    }
}

// ---------------------------------------------------------------------------
// K4: one block per (b,t) row. Unflagged rows (the overwhelmingly common
// case) write zeros. Flagged rows take the exact fp32 slow path.
__global__ __launch_bounds__(256)
void k4_output(const float* __restrict__ s_ema,
               const float* __restrict__ spikes,
               const float* __restrict__ W1,
               const float* __restrict__ Wr,
               const float* __restrict__ W2,
               const unsigned int* __restrict__ flags,
               float* __restrict__ out) {
    const int row = blockIdx.x;          // 0..R_-1
    const int tid = threadIdx.x;
    float4 o = {0.f, 0.f, 0.f, 0.f};

    if (flags[row] == 0u) {              // wave-uniform branch (per block)
        *(float4*)&out[(size_t)row * D_ + tid * 4] = o;
        return;
    }

    __shared__ float se[D_];
    __shared__ float sp[D_];
    __shared__ float red[256];
    __shared__ int nspk;
    __shared__ int spk_list[256];

    for (int i = tid; i < D_; i += 256) {
        se[i] = s_ema[(size_t)row * D_ + i];
        sp[i] = spikes[(size_t)row * D_ + i];
    }
    if (tid == 0) nspk = 0;
    __syncthreads();

    for (int f0 = 0; f0 < F_; f0 += 256) {
        int f = f0 + tid;
        float mix = 0.f;
        for (int k = 0; k < D_; ++k) mix += se[k] * W1[(size_t)f * D_ + k];
        if (mix > 0.5f) {
            int idx = atomicAdd(&nspk, 1);
            spk_list[idx] = f;
        }
        __syncthreads();
        int n = nspk;
        for (int i = 0; i < n; ++i) {
            int fs = spk_list[i];
            float part = 0.f;
#pragma unroll
            for (int k = 0; k < 4; ++k)
                part += sp[tid * 4 + k] * Wr[(size_t)fs * D_ + tid * 4 + k];
            red[tid] = part;
            __syncthreads();
            for (int sft = 128; sft > 0; sft >>= 1) {
                if (tid < sft) red[tid] += red[tid + sft];
                __syncthreads();
            }
            float r = 1.f / (1.f + expf(-red[0]));
            __syncthreads();
            o.x += r * W2[(size_t)(tid * 4 + 0) * F_ + fs];
            o.y += r * W2[(size_t)(tid * 4 + 1) * F_ + fs];
            o.z += r * W2[(size_t)(tid * 4 + 2) * F_ + fs];
            o.w += r * W2[(size_t)(tid * 4 + 3) * F_ + fs];
        }
        __syncthreads();
        if (tid == 0) nspk = 0;
        __syncthreads();
    }
    *(float4*)&out[(size_t)row * D_ + tid * 4] = o;
}

// ---------------------------------------------------------------------------
extern "C" void kernel_launch(void* const* d_in, const int* in_sizes, int n_in,
                              void* d_out, int out_size, void* d_ws, size_t ws_size,
                              hipStream_t stream) {
    const float* spikes = (const float*)d_in[0];   // [B,T,D]
    const float* W1     = (const float*)d_in[1];   // [F,D]
    const float* W2     = (const float*)d_in[2];   // [D,F]
    const float* Wr     = (const float*)d_in[3];   // [F,D]
    float* out = (float*)d_out;                    // [B,T,D]

    // workspace layout (~59.3 MB total)
    char* ws = (char*)d_ws;
    float* s_ema       = (float*)ws;                               // R_*D_ fp32
    float* seg_sum     = (float*)(ws + (size_t)R_ * D_ * 4);       // B_*SEG_*D_
    float* start_state = seg_sum + (size_t)B_ * SEG_ * D_;         // B_*SEG_*D_
    unsigned int* flags = (unsigned int*)(start_state + (size_t)B_ * SEG_ * D_); // R_
    ushort_t* a_bf = (ushort_t*)(flags + R_);                      // R_*D_ bf16
    ushort_t* w_bf = a_bf + (size_t)R_ * D_;                       // F_*D_ bf16

    const float dpowL = (float)pow(0.9, (double)L_);   // 0.9^128

    k0_zero_flags<<<(R_ + 255) / 256, 256, 0, stream>>>(flags);
    k1a_ema_local<<<(B_ * SEG_ * D_) / 256, 256, 0, stream>>>(spikes, s_ema, seg_sum);
    k1b_seg_scan<<<(B_ * D_) / 256, 256, 0, stream>>>(seg_sum, start_state, dpowL);
    k1c_fixup<<<(B_ * SEG_ * D_) / 256, 256, 0, stream>>>(s_ema, start_state, a_bf);
    k1w_w1_to_bf16<<<(F_ * D_ / 4) / 256, 256, 0, stream>>>(W1, w_bf);

    dim3 g2(F_ / 128, R_ / 128);
    k2_mfma_flags<<<g2, 256, 0, stream>>>(a_bf, w_bf, flags);

    k4_output<<<R_, 256, 0, stream>>>(s_ema, spikes, W1, Wr, W2, flags, out);
}

// Round 3
// 217.638 us; speedup vs baseline: 4.9201x; 1.1074x over previous
//
#include <hip/hip_runtime.h>
#include <math.h>

// Problem constants (match reference)
#define B_    4
#define T_    2048
#define D_    1024
#define F_    4096
#define R_    (B_*T_)      // 8192 rows (b,t)
#define SEG_  64           // segments per time-chain
#define L_    (T_/SEG_)    // 32 steps per segment
#define DECAYF 0.9f
#define OMDF   0.1f        // 1 - decay
// Flag threshold deliberately below 0.5 so the fallback (which re-tests at
// exactly 0.5 in fp32) can never miss a spike the flags skipped. bf16-input
// GEMM error is bounded ~6e-3 worst case; margin 0.05 is ~10x that.
#define FLAG_THRESH 0.45f

typedef unsigned short ushort_t;
typedef __attribute__((ext_vector_type(8))) __bf16 bf16x8;
typedef __attribute__((ext_vector_type(4))) float f32x4;

__device__ __forceinline__ ushort_t bf16r(float f) {
    unsigned u = __float_as_uint(f);
    unsigned r = (u + 0x7FFFu + ((u >> 16) & 1u)) >> 16;
    return (ushort_t)r;
}

__device__ __forceinline__ void gload_lds16(const void* g, void* l) {
    __builtin_amdgcn_global_load_lds(
        (const __attribute__((address_space(1))) unsigned int*)g,
        (__attribute__((address_space(3))) unsigned int*)l, 16, 0, 0);
}

// ---------------------------------------------------------------------------
// KA: fused prologue. Grid-partitioned roles:
//   blocks [0, 4096):       W1 fp32 -> bf16 (F_*D_/4 float4s)
//   blocks [4096, 4352):    per-segment EMA end-state (seg_sum), float4/thread
//   blocks [4352, 4384):    zero the 8192 per-row spike flags
#define KA_W1_BLOCKS  4096
#define KA_SEG_BLOCKS 256
#define KA_FLAG_BLOCKS 32

__global__ __launch_bounds__(256)
void kA_prologue(const float* __restrict__ spikes,
                 const float* __restrict__ W1,
                 ushort_t* __restrict__ w_bf,
                 float* __restrict__ seg_sum,
                 unsigned int* __restrict__ flags) {
    const int bid = blockIdx.x;
    const int tid = threadIdx.x;
    if (bid < KA_W1_BLOCKS) {
        int i = bid * 256 + tid;                  // float4 index
        float4 v = ((const float4*)W1)[i];
        ushort4 o;
        o.x = bf16r(v.x); o.y = bf16r(v.y); o.z = bf16r(v.z); o.w = bf16r(v.w);
        ((ushort4*)w_bf)[i] = o;
    } else if (bid < KA_W1_BLOCKS + KA_SEG_BLOCKS) {
        int t = (bid - KA_W1_BLOCKS) * 256 + tid; // B_*SEG_*D_/4 threads
        int dg = t & (D_ / 4 - 1);
        int s = (t >> 8) & (SEG_ - 1);
        int b = t >> 14;
        const float4* sp4 = (const float4*)spikes;
        const int base = (b * T_ + s * L_) * (D_ / 4) + dg;
        float4 e = {0.f, 0.f, 0.f, 0.f};
#pragma unroll 8
        for (int k = 0; k < L_; ++k) {
            float4 x = sp4[base + k * (D_ / 4)];
            e.x = DECAYF * e.x + OMDF * x.x;
            e.y = DECAYF * e.y + OMDF * x.y;
            e.z = DECAYF * e.z + OMDF * x.z;
            e.w = DECAYF * e.w + OMDF * x.w;
        }
        ((float4*)seg_sum)[(b * SEG_ + s) * (D_ / 4) + dg] = e;
    } else {
        int i = (bid - KA_W1_BLOCKS - KA_SEG_BLOCKS) * 256 + tid;
        if (i < R_) flags[i] = 0u;
    }
}

// ---------------------------------------------------------------------------
// KB: sequential scan across the 64 segments of each (b,d) chain.
// start_state[b][s][d] = EMA state entering segment s.
__global__ void kB_seg_scan(const float* __restrict__ seg_sum,
                            float* __restrict__ start_state,
                            float dpowL) {
    int tid = blockIdx.x * blockDim.x + threadIdx.x;   // B_*D_ threads
    int d = tid & (D_ - 1);
    int b = tid / D_;
    float carry = 0.f;
#pragma unroll 8
    for (int s = 0; s < SEG_; ++s) {
        int idx = (b * SEG_ + s) * D_ + d;
        start_state[idx] = carry;
        carry = dpowL * carry + seg_sum[idx];
    }
}

// ---------------------------------------------------------------------------
// KC: recompute segment-local EMA seeded with start_state; emit bf16 only.
__global__ __launch_bounds__(256)
void kC_ema_bf16(const float* __restrict__ spikes,
                 const float* __restrict__ start_state,
                 ushort_t* __restrict__ a_bf) {
    int t = blockIdx.x * 256 + threadIdx.x;            // B_*SEG_*D_/4 threads
    int dg = t & (D_ / 4 - 1);
    int s = (t >> 8) & (SEG_ - 1);
    int b = t >> 14;
    const float4* sp4 = (const float4*)spikes;
    const int base = (b * T_ + s * L_) * (D_ / 4) + dg;
    float4 e = ((const float4*)start_state)[(b * SEG_ + s) * (D_ / 4) + dg];
#pragma unroll 8
    for (int k = 0; k < L_; ++k) {
        float4 x = sp4[base + k * (D_ / 4)];
        e.x = DECAYF * e.x + OMDF * x.x;
        e.y = DECAYF * e.y + OMDF * x.y;
        e.z = DECAYF * e.z + OMDF * x.z;
        e.w = DECAYF * e.w + OMDF * x.w;
        ushort4 o;
        o.x = bf16r(e.x); o.y = bf16r(e.y); o.z = bf16r(e.z); o.w = bf16r(e.w);
        ((ushort4*)a_bf)[base + k * (D_ / 4)] = o;
    }
}

// ---------------------------------------------------------------------------
// K2: bf16 MFMA GEMM, flags-only epilogue (C is never materialized).
// 128x128 tile, BK=64, 4 waves in 2x2, each wave 4x4 grid of 16x16x32 MFMAs.
// LDS: k-major rows (128 B/row), 16B chunks XOR-swizzled by (row&7) so both
// the global_load_lds staging (wave-uniform base + lane*16) and the
// ds_read_b128 fragment reads are conflict-free (<=2-way).
__global__ __launch_bounds__(256)
void k2_mfma_flags(const ushort_t* __restrict__ A,    // s_ema bf16 [R_ x D_]
                   const ushort_t* __restrict__ Bw,   // W1 bf16    [F_ x D_]
                   unsigned int* __restrict__ flags) {
    __shared__ ushort_t lA[128 * 64];
    __shared__ ushort_t lB[128 * 64];
    const int tid = threadIdx.x;
    const int w = tid >> 6;
    const int lane = tid & 63;
    const int m0 = blockIdx.y * 128;
    const int n0 = blockIdx.x * 128;
    const int wm = w >> 1, wn = w & 1;

    f32x4 acc[4][4] = {};

    const int rown = lane & 15;
    const int quad = lane >> 4;

    for (int k0 = 0; k0 < D_; k0 += 64) {
        __syncthreads();   // previous iter's LDS reads must complete
#pragma unroll
        for (int r = 0; r < 4; ++r) {
            const int Ibase = r * 256 + w * 64;
            const int I = Ibase + lane;
            const int row = I >> 3;
            const int cl = (I & 7) ^ (row & 7);    // logical chunk for this slot
            gload_lds16(&A [(size_t)(m0 + row) * D_ + k0 + cl * 8], &lA[Ibase * 8]);
            gload_lds16(&Bw[(size_t)(n0 + row) * D_ + k0 + cl * 8], &lB[Ibase * 8]);
        }
        __syncthreads();   // drains vmcnt: staged data visible

#pragma unroll
        for (int kk = 0; kk < 2; ++kk) {
            bf16x8 af[4], bfr[4];
#pragma unroll
            for (int i = 0; i < 4; ++i) {
                const int ra = wm * 64 + i * 16 + rown;
                const int ca = (kk * 4 + quad) ^ (ra & 7);
                af[i] = *(const bf16x8*)&lA[ra * 64 + ca * 8];
                const int rb = wn * 64 + i * 16 + rown;
                const int cb = (kk * 4 + quad) ^ (rb & 7);
                bfr[i] = *(const bf16x8*)&lB[rb * 64 + cb * 8];
            }
#pragma unroll
            for (int i = 0; i < 4; ++i)
#pragma unroll
                for (int j = 0; j < 4; ++j)
                    acc[i][j] = __builtin_amdgcn_mfma_f32_16x16x32_bf16(
                        af[i], bfr[j], acc[i][j], 0, 0, 0);
        }
    }

    // Epilogue: per-row spike flags. C/D layout: col=lane&15, row=quad*4+reg.
#pragma unroll
    for (int i = 0; i < 4; ++i) {
#pragma unroll
        for (int v = 0; v < 4; ++v) {
            float mx =        acc[i][0][v];
            mx = fmaxf(mx,    acc[i][1][v]);
            mx = fmaxf(mx,    acc[i][2][v]);
            mx = fmaxf(mx,    acc[i][3][v]);
            if (mx > FLAG_THRESH)
                atomicOr(&flags[m0 + wm * 64 + i * 16 + quad * 4 + v], 1u);
        }
    }
}

// ---------------------------------------------------------------------------
// K4: one block per (b,t) row. Unflagged rows (the overwhelmingly common
// case) write zeros. Flagged rows take the exact fp32 slow path, rebuilding
// the EMA row from start_state + <=32 spike rows (s_ema is not materialized).
__global__ __launch_bounds__(256)
void k4_output(const float* __restrict__ spikes,
               const float* __restrict__ start_state,
               const float* __restrict__ W1,
               const float* __restrict__ Wr,
               const float* __restrict__ W2,
               const unsigned int* __restrict__ flags,
               float* __restrict__ out) {
    const int row = blockIdx.x;          // 0..R_-1
    const int tid = threadIdx.x;
    float4 o = {0.f, 0.f, 0.f, 0.f};

    if (flags[row] == 0u) {              // wave-uniform branch (per block)
        *(float4*)&out[(size_t)row * D_ + tid * 4] = o;
        return;
    }

    __shared__ float se[D_];
    __shared__ float sp[D_];
    __shared__ float red[256];
    __shared__ int nspk;
    __shared__ int spk_list[256];

    const int b = row / T_;
    const int t = row % T_;
    const int seg = t / L_;
    const int off = t % L_;
    const int segbase = (b * T_ + seg * L_) * D_;

    for (int i = tid; i < D_; i += 256) {
        float e = start_state[(b * SEG_ + seg) * D_ + i];
        for (int j = 0; j <= off; ++j)
            e = DECAYF * e + OMDF * spikes[segbase + j * D_ + i];
        se[i] = e;
        sp[i] = spikes[(size_t)row * D_ + i];
    }
    if (tid == 0) nspk = 0;
    __syncthreads();

    for (int f0 = 0; f0 < F_; f0 += 256) {
        int f = f0 + tid;
        float mix = 0.f;
        for (int k = 0; k < D_; ++k) mix += se[k] * W1[(size_t)f * D_ + k];
        if (mix > 0.5f) {
            int idx = atomicAdd(&nspk, 1);
            spk_list[idx] = f;
        }
        __syncthreads();
        int n = nspk;
        for (int i = 0; i < n; ++i) {
            int fs = spk_list[i];
            float part = 0.f;
#pragma unroll
            for (int k = 0; k < 4; ++k)
                part += sp[tid * 4 + k] * Wr[(size_t)fs * D_ + tid * 4 + k];
            red[tid] = part;
            __syncthreads();
            for (int sft = 128; sft > 0; sft >>= 1) {
                if (tid < sft) red[tid] += red[tid + sft];
                __syncthreads();
            }
            float r = 1.f / (1.f + expf(-red[0]));
            __syncthreads();
            o.x += r * W2[(size_t)(tid * 4 + 0) * F_ + fs];
            o.y += r * W2[(size_t)(tid * 4 + 1) * F_ + fs];
            o.z += r * W2[(size_t)(tid * 4 + 2) * F_ + fs];
            o.w += r * W2[(size_t)(tid * 4 + 3) * F_ + fs];
        }
        __syncthreads();
        if (tid == 0) nspk = 0;
        __syncthreads();
    }
    *(float4*)&out[(size_t)row * D_ + tid * 4] = o;
}

// ---------------------------------------------------------------------------
extern "C" void kernel_launch(void* const* d_in, const int* in_sizes, int n_in,
                              void* d_out, int out_size, void* d_ws, size_t ws_size,
                              hipStream_t stream) {
    const float* spikes = (const float*)d_in[0];   // [B,T,D]
    const float* W1     = (const float*)d_in[1];   // [F,D]
    const float* W2     = (const float*)d_in[2];   // [D,F]
    const float* Wr     = (const float*)d_in[3];   // [F,D]
    float* out = (float*)d_out;                    // [B,T,D]

    // workspace layout (~27.3 MB total)
    char* ws = (char*)d_ws;
    float* seg_sum     = (float*)ws;                               // B_*SEG_*D_
    float* start_state = seg_sum + (size_t)B_ * SEG_ * D_;         // B_*SEG_*D_
    unsigned int* flags = (unsigned int*)(start_state + (size_t)B_ * SEG_ * D_); // R_
    ushort_t* a_bf = (ushort_t*)(flags + R_);                      // R_*D_ bf16
    ushort_t* w_bf = a_bf + (size_t)R_ * D_;                       // F_*D_ bf16

    const float dpowL = (float)pow(0.9, (double)L_);   // 0.9^32

    kA_prologue<<<KA_W1_BLOCKS + KA_SEG_BLOCKS + KA_FLAG_BLOCKS, 256, 0, stream>>>(
        spikes, W1, w_bf, seg_sum, flags);
    kB_seg_scan<<<(B_ * D_) / 256, 256, 0, stream>>>(seg_sum, start_state, dpowL);
    kC_ema_bf16<<<(B_ * SEG_ * D_ / 4) / 256, 256, 0, stream>>>(spikes, start_state, a_bf);

    dim3 g2(F_ / 128, R_ / 128);
    k2_mfma_flags<<<g2, 256, 0, stream>>>(a_bf, w_bf, flags);

    k4_output<<<R_, 256, 0, stream>>>(spikes, start_state, W1, Wr, W2, flags, out);
}

// Round 4
// 203.782 us; speedup vs baseline: 5.2546x; 1.0680x over previous
//
#include <hip/hip_runtime.h>
#include <math.h>

// Problem constants (match reference)
#define B_    4
#define T_    2048
#define D_    1024
#define F_    4096
#define R_    (B_*T_)      // 8192 rows (b,t)
#define SEG_  64           // segments per time-chain
#define L_    (T_/SEG_)    // 32 steps per segment
#define DECAYF 0.9f
#define OMDF   0.1f        // 1 - decay
// Flag threshold below 0.5: the k4 fallback re-tests at exactly 0.5 in fp32,
// so flags only need NO FALSE NEGATIVES. fp8(x8-scaled) GEMM error is
// ~1e-3 RMS (6-sigma ~7e-3); margin 0.05 is ~7x worst plausible error.
#define FLAG_THRESH 0.45f

typedef __attribute__((ext_vector_type(4))) int   i32x4;
typedef __attribute__((ext_vector_type(8))) int   i32x8;
typedef __attribute__((ext_vector_type(4))) float f32x4;

// pack 4 floats into 4 fp8 e4m3 bytes (byte0 = first arg)
__device__ __forceinline__ int pk_fp8x4(float x, float y, float z, float w) {
    int p = 0;
    p = __builtin_amdgcn_cvt_pk_fp8_f32(x, y, p, false);  // bytes 0,1
    p = __builtin_amdgcn_cvt_pk_fp8_f32(z, w, p, true);   // bytes 2,3
    return p;
}

__device__ __forceinline__ void gload_lds16(const void* g, void* l) {
    __builtin_amdgcn_global_load_lds(
        (const __attribute__((address_space(1))) unsigned int*)g,
        (__attribute__((address_space(3))) unsigned int*)l, 16, 0, 0);
}

// ---------------------------------------------------------------------------
// KA: fused prologue. Grid-partitioned roles:
//   blocks [0, 4096):       W1 fp32 -> fp8 e4m3, values x8 (scale 2^-3 in MFMA)
//   blocks [4096, 4352):    per-segment EMA end-state (seg_sum)
//   blocks [4352, 4384):    zero the 8192 per-row spike flags
#define KA_W1_BLOCKS  4096
#define KA_SEG_BLOCKS 256
#define KA_FLAG_BLOCKS 32

__global__ __launch_bounds__(256)
void kA_prologue(const float* __restrict__ spikes,
                 const float* __restrict__ W1,
                 unsigned char* __restrict__ w_f8,
                 float* __restrict__ seg_sum,
                 unsigned int* __restrict__ flags) {
    const int bid = blockIdx.x;
    const int tid = threadIdx.x;
    if (bid < KA_W1_BLOCKS) {
        int i = bid * 256 + tid;                  // float4 index
        float4 v = ((const float4*)W1)[i];
        ((int*)w_f8)[i] = pk_fp8x4(8.f*v.x, 8.f*v.y, 8.f*v.z, 8.f*v.w);
    } else if (bid < KA_W1_BLOCKS + KA_SEG_BLOCKS) {
        int t = (bid - KA_W1_BLOCKS) * 256 + tid; // B_*SEG_*D_/4 threads
        int dg = t & (D_ / 4 - 1);
        int s = (t >> 8) & (SEG_ - 1);
        int b = t >> 14;
        const float4* sp4 = (const float4*)spikes;
        const int base = (b * T_ + s * L_) * (D_ / 4) + dg;
        float4 e = {0.f, 0.f, 0.f, 0.f};
#pragma unroll 8
        for (int k = 0; k < L_; ++k) {
            float4 x = sp4[base + k * (D_ / 4)];
            e.x = DECAYF * e.x + OMDF * x.x;
            e.y = DECAYF * e.y + OMDF * x.y;
            e.z = DECAYF * e.z + OMDF * x.z;
            e.w = DECAYF * e.w + OMDF * x.w;
        }
        ((float4*)seg_sum)[(b * SEG_ + s) * (D_ / 4) + dg] = e;
    } else {
        int i = (bid - KA_W1_BLOCKS - KA_SEG_BLOCKS) * 256 + tid;
        if (i < R_) flags[i] = 0u;
    }
}

// ---------------------------------------------------------------------------
// KB: weighted Kogge-Stone scan over the 64 segments of each (b,d) chain,
// one chain per 64-lane wave (lane = segment). 6 shuffle-FMA steps replace
// the 64-long serial loop. start_state[s] = inclusive_scan[s-1] (0 at s=0).
__global__ __launch_bounds__(256)
void kB_seg_scan(const float* __restrict__ seg_sum,
                 float* __restrict__ start_state) {
    int g = blockIdx.x * 256 + threadIdx.x;   // B_*D_*64 threads
    int s = g & 63;                           // segment = lane
    int c = g >> 6;                           // chain id: 0..B_*D_-1
    int d = c & (D_ - 1);
    int b = c >> 10;
    int idx = (b * SEG_ + s) * D_ + d;
    float v = seg_sum[idx];
    float wp = 0.0343368382f;                 // 0.9^32 (per-segment decay)
#pragma unroll
    for (int off = 1; off < SEG_; off <<= 1) {
        float u = __shfl_up(v, off, 64);
        if (s >= off) v += wp * u;
        wp *= wp;                             // w^1, w^2, w^4, ...
    }
    float pv = __shfl_up(v, 1, 64);
    start_state[idx] = (s == 0) ? 0.f : pv;
}

// ---------------------------------------------------------------------------
// KC: recompute segment-local EMA seeded with start_state; emit fp8 (x8).
__global__ __launch_bounds__(256)
void kC_ema_fp8(const float* __restrict__ spikes,
                const float* __restrict__ start_state,
                unsigned char* __restrict__ a_f8) {
    int t = blockIdx.x * 256 + threadIdx.x;            // B_*SEG_*D_/4 threads
    int dg = t & (D_ / 4 - 1);
    int s = (t >> 8) & (SEG_ - 1);
    int b = t >> 14;
    const float4* sp4 = (const float4*)spikes;
    const int base = (b * T_ + s * L_) * (D_ / 4) + dg;
    float4 e = ((const float4*)start_state)[(b * SEG_ + s) * (D_ / 4) + dg];
#pragma unroll 8
    for (int k = 0; k < L_; ++k) {
        float4 x = sp4[base + k * (D_ / 4)];
        e.x = DECAYF * e.x + OMDF * x.x;
        e.y = DECAYF * e.y + OMDF * x.y;
        e.z = DECAYF * e.z + OMDF * x.z;
        e.w = DECAYF * e.w + OMDF * x.w;
        ((int*)a_f8)[base + k * (D_ / 4)] =
            pk_fp8x4(8.f*e.x, 8.f*e.y, 8.f*e.z, 8.f*e.w);
    }
}

// ---------------------------------------------------------------------------
// K2: MX-fp8 MFMA GEMM (mfma_scale 16x16x128, uniform e8m0 scales = 2^-3 on
// both operands so acc == sum a*w exactly in scale), flags-only epilogue.
// 128x128 tile, BK=128: LDS rows are 128 B = 8 x 16B chunks — identical
// swizzle geometry to the verified bf16 kernel. 4 waves 2x2, each wave 4x4
// grid of 16x16x128 MFMAs. Frag: lane (kgrp=lane>>4) holds k-bytes
// [kgrp*32, kgrp*32+32) of its row -> two swizzled ds_read_b128.
__global__ __launch_bounds__(256)
void k2_mfma_flags(const unsigned char* __restrict__ A,   // a_f8 [R_ x D_]
                   const unsigned char* __restrict__ Bw,  // w_f8 [F_ x D_]
                   unsigned int* __restrict__ flags) {
    __shared__ __align__(16) unsigned char lA[128 * 128];
    __shared__ __align__(16) unsigned char lB[128 * 128];
    const int tid = threadIdx.x;
    const int w = tid >> 6;
    const int lane = tid & 63;
    const int m0 = blockIdx.y * 128;
    const int n0 = blockIdx.x * 128;
    const int wm = w >> 1, wn = w & 1;
    const int rown = lane & 15;
    const int kgrp = lane >> 4;
    const int c0 = 2 * kgrp;

    f32x4 acc[4][4] = {};

    for (int k0 = 0; k0 < D_; k0 += 128) {
        __syncthreads();   // previous iter's LDS reads must complete
        // Stage A and B tiles: 1024 16B-chunks each; 4 rounds x 4 waves x 64.
#pragma unroll
        for (int r = 0; r < 4; ++r) {
            const int Ibase = r * 256 + w * 64;
            const int I = Ibase + lane;
            const int row = I >> 3;
            const int cl = (I & 7) ^ (row & 7);    // XOR-swizzled chunk
            gload_lds16(&A [(size_t)(m0 + row) * D_ + k0 + cl * 16], &lA[Ibase * 16]);
            gload_lds16(&Bw[(size_t)(n0 + row) * D_ + k0 + cl * 16], &lB[Ibase * 16]);
        }
        __syncthreads();   // drains vmcnt: staged data visible

        i32x8 af[4], bf[4];
#pragma unroll
        for (int i = 0; i < 4; ++i) {
            const int ra = wm * 64 + i * 16 + rown;
            i32x4 lo = *(const i32x4*)&lA[ra * 128 + ((c0    ) ^ (ra & 7)) * 16];
            i32x4 hi = *(const i32x4*)&lA[ra * 128 + ((c0 + 1) ^ (ra & 7)) * 16];
            af[i] = (i32x8){lo.x, lo.y, lo.z, lo.w, hi.x, hi.y, hi.z, hi.w};
            const int rb = wn * 64 + i * 16 + rown;
            i32x4 lo2 = *(const i32x4*)&lB[rb * 128 + ((c0    ) ^ (rb & 7)) * 16];
            i32x4 hi2 = *(const i32x4*)&lB[rb * 128 + ((c0 + 1) ^ (rb & 7)) * 16];
            bf[i] = (i32x8){lo2.x, lo2.y, lo2.z, lo2.w, hi2.x, hi2.y, hi2.z, hi2.w};
        }
#pragma unroll
        for (int i = 0; i < 4; ++i)
#pragma unroll
            for (int j = 0; j < 4; ++j)
                acc[i][j] = __builtin_amdgcn_mfma_scale_f32_16x16x128_f8f6f4(
                    af[i], bf[j], acc[i][j],
                    0, 0,          // cbsz: A fmt = fp8 e4m3, blgp: B fmt = fp8
                    0, 124,        // scaleA opsel, e8m0 124 = 2^-3
                    0, 124);       // scaleB opsel, e8m0 124 = 2^-3
    }

    // Epilogue: per-row spike flags. C/D layout: col=lane&15, row=quad*4+reg.
    const int quad = lane >> 4;
#pragma unroll
    for (int i = 0; i < 4; ++i) {
#pragma unroll
        for (int v = 0; v < 4; ++v) {
            float mx =     acc[i][0][v];
            mx = fmaxf(mx, acc[i][1][v]);
            mx = fmaxf(mx, acc[i][2][v]);
            mx = fmaxf(mx, acc[i][3][v]);
            if (mx > FLAG_THRESH)
                atomicOr(&flags[m0 + wm * 64 + i * 16 + quad * 4 + v], 1u);
        }
    }
}

// ---------------------------------------------------------------------------
// K4: one block per (b,t) row. Unflagged rows (the overwhelmingly common
// case) write zeros. Flagged rows take the exact fp32 slow path, rebuilding
// the EMA row from start_state + <=32 spike rows.
__global__ __launch_bounds__(256)
void k4_output(const float* __restrict__ spikes,
               const float* __restrict__ start_state,
               const float* __restrict__ W1,
               const float* __restrict__ Wr,
               const float* __restrict__ W2,
               const unsigned int* __restrict__ flags,
               float* __restrict__ out) {
    const int row = blockIdx.x;          // 0..R_-1
    const int tid = threadIdx.x;
    float4 o = {0.f, 0.f, 0.f, 0.f};

    if (flags[row] == 0u) {              // wave-uniform branch (per block)
        *(float4*)&out[(size_t)row * D_ + tid * 4] = o;
        return;
    }

    __shared__ float se[D_];
    __shared__ float sp[D_];
    __shared__ float red[256];
    __shared__ int nspk;
    __shared__ int spk_list[256];

    const int b = row / T_;
    const int t = row % T_;
    const int seg = t / L_;
    const int off = t % L_;
    const int segbase = (b * T_ + seg * L_) * D_;

    for (int i = tid; i < D_; i += 256) {
        float e = start_state[(b * SEG_ + seg) * D_ + i];
        for (int j = 0; j <= off; ++j)
            e = DECAYF * e + OMDF * spikes[segbase + j * D_ + i];
        se[i] = e;
        sp[i] = spikes[(size_t)row * D_ + i];
    }
    if (tid == 0) nspk = 0;
    __syncthreads();

    for (int f0 = 0; f0 < F_; f0 += 256) {
        int f = f0 + tid;
        float mix = 0.f;
        for (int k = 0; k < D_; ++k) mix += se[k] * W1[(size_t)f * D_ + k];
        if (mix > 0.5f) {
            int idx = atomicAdd(&nspk, 1);
            spk_list[idx] = f;
        }
        __syncthreads();
        int n = nspk;
        for (int i = 0; i < n; ++i) {
            int fs = spk_list[i];
            float part = 0.f;
#pragma unroll
            for (int k = 0; k < 4; ++k)
                part += sp[tid * 4 + k] * Wr[(size_t)fs * D_ + tid * 4 + k];
            red[tid] = part;
            __syncthreads();
            for (int sft = 128; sft > 0; sft >>= 1) {
                if (tid < sft) red[tid] += red[tid + sft];
                __syncthreads();
            }
            float r = 1.f / (1.f + expf(-red[0]));
            __syncthreads();
            o.x += r * W2[(size_t)(tid * 4 + 0) * F_ + fs];
            o.y += r * W2[(size_t)(tid * 4 + 1) * F_ + fs];
            o.z += r * W2[(size_t)(tid * 4 + 2) * F_ + fs];
            o.w += r * W2[(size_t)(tid * 4 + 3) * F_ + fs];
        }
        __syncthreads();
        if (tid == 0) nspk = 0;
        __syncthreads();
    }
    *(float4*)&out[(size_t)row * D_ + tid * 4] = o;
}

// ---------------------------------------------------------------------------
extern "C" void kernel_launch(void* const* d_in, const int* in_sizes, int n_in,
                              void* d_out, int out_size, void* d_ws, size_t ws_size,
                              hipStream_t stream) {
    const float* spikes = (const float*)d_in[0];   // [B,T,D]
    const float* W1     = (const float*)d_in[1];   // [F,D]
    const float* W2     = (const float*)d_in[2];   // [D,F]
    const float* Wr     = (const float*)d_in[3];   // [F,D]
    float* out = (float*)d_out;                    // [B,T,D]

    // workspace layout (~14.3 MB total)
    char* ws = (char*)d_ws;
    float* seg_sum      = (float*)ws;                                // 1 MB
    float* start_state  = seg_sum + (size_t)B_ * SEG_ * D_;          // 1 MB
    unsigned int* flags = (unsigned int*)(start_state + (size_t)B_ * SEG_ * D_); // 32 KB
    unsigned char* a_f8 = (unsigned char*)(flags + R_);              // 8 MB
    unsigned char* w_f8 = a_f8 + (size_t)R_ * D_;                    // 4 MB

    kA_prologue<<<KA_W1_BLOCKS + KA_SEG_BLOCKS + KA_FLAG_BLOCKS, 256, 0, stream>>>(
        spikes, W1, w_f8, seg_sum, flags);
    kB_seg_scan<<<(B_ * D_ * 64) / 256, 256, 0, stream>>>(seg_sum, start_state);
    kC_ema_fp8<<<(B_ * SEG_ * D_ / 4) / 256, 256, 0, stream>>>(spikes, start_state, a_f8);

    dim3 g2(F_ / 128, R_ / 128);
    k2_mfma_flags<<<g2, 256, 0, stream>>>(a_f8, w_f8, flags);

    k4_output<<<R_, 256, 0, stream>>>(spikes, start_state, W1, Wr, W2, flags, out);
}